// Round 5
// baseline (674.264 us; speedup 1.0000x reference)
//
#include <hip/hip_runtime.h>
#include <math.h>

#define TOK 32768
#define CH  256
#define HIDN 1024
#define NE  8
#define BE  10240
#define CNT_STRIDE 64  // ints between expert counters (256B, separate cache lines)

typedef __attribute__((ext_vector_type(8))) short bf16x8;
typedef __attribute__((ext_vector_type(4))) float f32x4;

__device__ __forceinline__ unsigned short f2bf(float f) {
    unsigned u = __builtin_bit_cast(unsigned, f);
    unsigned r = 0x7FFFu + ((u >> 16) & 1u);
    return (unsigned short)((u + r) >> 16);
}
__device__ __forceinline__ float bf2f(unsigned short u) {
    return __builtin_bit_cast(float, (unsigned)u << 16);
}

__global__ void k_init(int* cnt) {
    cnt[threadIdx.x] = 0;
}

// Depthwise 7x7 conv + bias, NCHW in -> NHWC (token-major) out.
__global__ __launch_bounds__(256) void k_conv(const float* __restrict__ in,
                                              const float* __restrict__ kern,
                                              const float* __restrict__ bias,
                                              float* __restrict__ xc) {
    __shared__ float kw[49];
    int t = threadIdx.x;
    int id = blockIdx.x * 256 + t;
    int x = id & 31, y = (id >> 5) & 31, c = (id >> 10) & 255, n = id >> 18;
    if (t < 49) kw[t] = kern[c * 49 + t];
    __syncthreads();
    const float* ip = in + (size_t)(n * CH + c) * 1024;
    float s = bias[c];
#pragma unroll
    for (int dy = -3; dy <= 3; ++dy) {
        int yy = y + dy;
        if ((unsigned)yy < 32u) {
            const float* rp = ip + yy * 32;
#pragma unroll
            for (int dx = -3; dx <= 3; ++dx) {
                int xx = x + dx;
                if ((unsigned)xx < 32u) s += rp[xx] * kw[(dy + 3) * 7 + (dx + 3)];
            }
        }
    }
    int token = n * 1024 + y * 32 + x;
    xc[(size_t)token * CH + c] = s;
}

// LayerNorm + router top-2 (no atomics). One wave per token.
__global__ __launch_bounds__(256) void k_ln_router(const float* __restrict__ xc,
                                                   const float* __restrict__ gamma,
                                                   const float* __restrict__ beta,
                                                   const float* __restrict__ rw,
                                                   unsigned short* __restrict__ xln,
                                                   int* __restrict__ e01,
                                                   float2* __restrict__ gates) {
    int lane = threadIdx.x & 63;
    int wid  = threadIdx.x >> 6;
    int tok  = blockIdx.x * 4 + wid;

    const float4* xr = (const float4*)(xc + (size_t)tok * CH);
    float4 v = xr[lane];
    float s = v.x + v.y + v.z + v.w;
    float q = v.x * v.x + v.y * v.y + v.z * v.z + v.w * v.w;
#pragma unroll
    for (int m = 1; m < 64; m <<= 1) { s += __shfl_xor(s, m); q += __shfl_xor(q, m); }
    float mean = s * (1.0f / 256.0f);
    float var  = q * (1.0f / 256.0f) - mean * mean;
    float rstd = rsqrtf(var + 1e-6f);

    float4 g4 = ((const float4*)gamma)[lane];
    float4 b4 = ((const float4*)beta)[lane];
    float xn[4];
    xn[0] = (v.x - mean) * rstd * g4.x + b4.x;
    xn[1] = (v.y - mean) * rstd * g4.y + b4.y;
    xn[2] = (v.z - mean) * rstd * g4.z + b4.z;
    xn[3] = (v.w - mean) * rstd * g4.w + b4.w;

    ushort4 pk;
    pk.x = f2bf(xn[0]); pk.y = f2bf(xn[1]); pk.z = f2bf(xn[2]); pk.w = f2bf(xn[3]);
    ((ushort4*)xln)[tok * 64 + lane] = pk;

    float p[8] = {0, 0, 0, 0, 0, 0, 0, 0};
    int c0 = lane * 4;
#pragma unroll
    for (int j = 0; j < 4; ++j) {
        const float* rwp = rw + (size_t)(c0 + j) * 8;
        float xv = xn[j];
#pragma unroll
        for (int e = 0; e < 8; ++e) p[e] += xv * rwp[e];
    }
#pragma unroll
    for (int m = 1; m < 64; m <<= 1) {
#pragma unroll
        for (int e = 0; e < 8; ++e) p[e] += __shfl_xor(p[e], m);
    }

    if (lane == 0) {
        int e0 = 0; float l0 = p[0];
#pragma unroll
        for (int e = 1; e < 8; ++e) if (p[e] > l0) { l0 = p[e]; e0 = e; }
        int e1 = -1; float l1 = -3.4e38f;
#pragma unroll
        for (int e = 0; e < 8; ++e) if (e != e0 && p[e] > l1) { l1 = p[e]; e1 = e; }
        float tt = expf(l1 - l0);
        float w0 = 1.0f / (1.0f + tt);
        e01[tok] = e0 | (e1 << 8);
        gates[tok] = make_float2(w0, 1.0f - w0);
    }
}

// Hierarchical capacity assignment: LDS counts + one global atomic per expert per block.
__global__ __launch_bounds__(256) void k_assign(const int* __restrict__ e01,
                                                int* __restrict__ cnt,
                                                int* __restrict__ row_token,
                                                int2* __restrict__ slots) {
    __shared__ int lcnt[8];
    __shared__ int base[8];
    int t = threadIdx.x;
    if (t < 8) lcnt[t] = 0;
    __syncthreads();
    int tok = blockIdx.x * 256 + t;
    int ee = e01[tok];
    int e0 = ee & 255, e1 = (ee >> 8) & 255;
    int lp0 = atomicAdd(&lcnt[e0], 1);
    int lp1 = atomicAdd(&lcnt[e1], 1);
    __syncthreads();
    if (t < 8) base[t] = atomicAdd(cnt + t * CNT_STRIDE, lcnt[t]);
    __syncthreads();
    int pos0 = base[e0] + lp0;
    int pos1 = base[e1] + lp1;
    int slot0 = (pos0 < BE) ? e0 * BE + pos0 : -1;
    int slot1 = (pos1 < BE) ? e1 * BE + pos1 : -1;
    if (slot0 >= 0) row_token[slot0] = tok;
    if (slot1 >= 0) row_token[slot1] = tok;
    slots[tok] = make_int2(slot0, slot1);
}

// Transpose R x S (f32) -> S x R (bf16), one matrix per blockIdx.z.
__global__ __launch_bounds__(256) void k_transpose(const float* __restrict__ in,
                                                   unsigned short* __restrict__ out,
                                                   int R, int S) {
    __shared__ float tile[32][33];
    size_t mb = (size_t)blockIdx.z * R * S;
    in += mb; out += mb;
    int tx = threadIdx.x & 31, ty = threadIdx.x >> 5;
    int sc = blockIdx.x * 32 + tx;
#pragma unroll
    for (int i = 0; i < 4; ++i) {
        int r = blockIdx.y * 32 + ty + i * 8;
        tile[ty + i * 8][tx] = in[(size_t)r * S + sc];
    }
    __syncthreads();
    int rc = blockIdx.y * 32 + tx;
#pragma unroll
    for (int i = 0; i < 4; ++i) {
        int sr = blockIdx.x * 32 + ty + i * 8;
        out[(size_t)sr * R + rc] = f2bf(tile[tx][ty + i * 8]);
    }
}

// Fused expert MLP, X-in-registers: per block = 32 rows of one expert,
// expert = bid&7 (XCD-pinned). Each wave holds ALL 32 rows of X in VGPRs
// (A-part has ZERO LDS reads; only H round-trips through LDS, 8KB dbuf).
// hid in 8 chunks of 128; iteration hc runs A(hc) || B(hc-1) then 1 barrier.
__global__ __launch_bounds__(256, 3) void k_mlp(const unsigned short* __restrict__ xln,
                                                const unsigned short* __restrict__ w1t,  // [E][HID][C]
                                                const unsigned short* __restrict__ w2t,  // [E][C][HID]
                                                const float* __restrict__ b1,
                                                const float* __restrict__ b2,
                                                const int* __restrict__ cnt,
                                                const int* __restrict__ row_token,
                                                unsigned short* __restrict__ Y) {
    int bid = blockIdx.x;
    int e = bid & 7;                 // XCD pinning: all blocks of expert e on XCD e
    int row0 = (bid >> 3) * 32;
    int nrows = min(cnt[e * CNT_STRIDE], BE);
    if (row0 >= nrows) return;

    __shared__ unsigned short Xs[32 * 256];     // 16KB, rows 512B, chunk ^ r; reused for Y staging
    __shared__ unsigned short Hs[2][32 * 128];  // 8KB each, rows 256B, chunk ^ (r&15)
    __shared__ int tokl[32];

    int t = threadIdx.x;
    if (t < 32) {
        int r = row0 + t;
        tokl[t] = (r < nrows) ? row_token[e * BE + r] : 0;
    }
    __syncthreads();

    {   // stage Xs (16KB): 8 threads/row, 16B chunks, chunk ^= r
#pragma unroll
        for (int i = 0; i < 4; ++i) {
            int flat = i * 4096 + t * 16;
            int r = flat >> 9, chunk = (flat >> 4) & 31;
            const char* src = (const char*)(xln + (size_t)tokl[r] * 256);
            *(int4*)((char*)Xs + r * 512 + ((chunk ^ r) << 4)) = *(const int4*)(src + (flat & 511));
        }
    }
    __syncthreads();

    int lane = t & 63, w = t >> 6;
    int l15 = lane & 15, l4 = lane >> 4, odd = l15 & 1;
    const unsigned short* w1e = w1t + (size_t)e * HIDN * 256;
    const unsigned short* w2e = w2t + (size_t)e * 256 * HIDN;

    // ---- X -> registers: all 32 rows, full K=256 (16 frags, 64 VGPR)
    bf16x8 xf[2][8];
#pragma unroll
    for (int m = 0; m < 2; ++m)
#pragma unroll
        for (int ks = 0; ks < 8; ++ks) {
            int r = m * 16 + l15;
            int chunk = ks * 4 + l4;
            xf[m][ks] = *(const bf16x8*)((const char*)Xs + r * 512 + ((chunk ^ r) << 4));
        }

    f32x4 yacc[2][4];
#pragma unroll
    for (int m = 0; m < 2; ++m)
#pragma unroll
        for (int nc = 0; nc < 4; ++nc) yacc[m][nc] = f32x4{0.f, 0.f, 0.f, 0.f};

    // A-part: H[32 rows][w*32 .. +32) of hid chunk hc; gelu; write Hs[hc&1]
    auto Apart = [&](int hc) {
        f32x4 hacc[2][2];
#pragma unroll
        for (int m = 0; m < 2; ++m)
#pragma unroll
            for (int nf = 0; nf < 2; ++nf) hacc[m][nf] = f32x4{0.f, 0.f, 0.f, 0.f};
#pragma unroll
        for (int ks = 0; ks < 8; ++ks) {
#pragma unroll
            for (int nf = 0; nf < 2; ++nf) {
                int nA = hc * 128 + w * 32 + nf * 16 + l15;
                bf16x8 bfrag = *(const bf16x8*)(w1e + (size_t)nA * 256 + ks * 32 + l4 * 8);
                hacc[0][nf] = __builtin_amdgcn_mfma_f32_16x16x32_bf16(xf[0][ks], bfrag, hacc[0][nf], 0, 0, 0);
                hacc[1][nf] = __builtin_amdgcn_mfma_f32_16x16x32_bf16(xf[1][ks], bfrag, hacc[1][nf], 0, 0, 0);
            }
        }
        char* Hcur = (char*)Hs[hc & 1];
#pragma unroll
        for (int nf = 0; nf < 2; ++nf) {
            int col = w * 32 + nf * 16 + l15;
            float bb = b1[e * HIDN + hc * 128 + col];
            int colb = (col & ~1) * 2;
            int chunk0 = colb >> 4;
#pragma unroll
            for (int m = 0; m < 2; ++m) {
                float gl[4], ex[4];
#pragma unroll
                for (int j = 0; j < 4; ++j) {
                    float vv = hacc[m][nf][j] + bb;
                    float tt = vv * (1.0f + 0.044715f * vv * vv);
                    gl[j] = vv * __builtin_amdgcn_rcpf(1.0f + __builtin_amdgcn_exp2f(-2.3022100f * tt));
                }
#pragma unroll
                for (int j = 0; j < 4; ++j) ex[j] = __shfl_xor(gl[j], 1);
#pragma unroll
                for (int jj = 0; jj < 2; ++jj) {
                    int j = odd * 2 + jj;
                    int r = m * 16 + l4 * 4 + j;
                    unsigned lo = f2bf(odd ? ex[j] : gl[j]);
                    unsigned hi = f2bf(odd ? gl[j] : ex[j]);
                    *(unsigned*)(Hcur + r * 256 + (((chunk0 ^ (r & 15)) << 4) | (colb & 15))) =
                        lo | (hi << 16);
                }
            }
        }
    };

    // B-part: yacc += gelu-H[hc] @ W2[hid chunk hc], wave covers cols [w*64, +64)
    auto Bpart = [&](int hc) {
        const char* Hp = (const char*)Hs[hc & 1];
#pragma unroll
        for (int ks = 0; ks < 4; ++ks) {
            bf16x8 aH[2];
#pragma unroll
            for (int m = 0; m < 2; ++m) {
                int r = m * 16 + l15;
                int chunk = ks * 4 + l4;
                aH[m] = *(const bf16x8*)(Hp + r * 256 + ((chunk ^ (r & 15)) << 4));
            }
#pragma unroll
            for (int nc = 0; nc < 4; ++nc) {
                int ncol = w * 64 + nc * 16 + l15;
                bf16x8 bW = *(const bf16x8*)(w2e + (size_t)ncol * HIDN + hc * 128 + ks * 32 + l4 * 8);
                yacc[0][nc] = __builtin_amdgcn_mfma_f32_16x16x32_bf16(aH[0], bW, yacc[0][nc], 0, 0, 0);
                yacc[1][nc] = __builtin_amdgcn_mfma_f32_16x16x32_bf16(aH[1], bW, yacc[1][nc], 0, 0, 0);
            }
        }
    };

    Apart(0);
    __syncthreads();
#pragma unroll
    for (int hc = 1; hc < 8; ++hc) {
        Apart(hc);       // writes Hs[hc&1]
        Bpart(hc - 1);   // reads  Hs[(hc-1)&1]
        __syncthreads();
    }
    Bpart(7);

    // ---- stage yacc (+b2, ->bf16) into Xs (dead), then coalesced copy-out
#pragma unroll
    for (int nc = 0; nc < 4; ++nc) {
        int col = w * 64 + nc * 16 + l15;
        float bb2 = b2[e * 256 + col];
        int colb = (col & ~1) * 2;
        int chunk0 = colb >> 4;
#pragma unroll
        for (int m = 0; m < 2; ++m) {
            float gl[4], ex[4];
#pragma unroll
            for (int j = 0; j < 4; ++j) gl[j] = yacc[m][nc][j] + bb2;
#pragma unroll
            for (int j = 0; j < 4; ++j) ex[j] = __shfl_xor(gl[j], 1);
#pragma unroll
            for (int jj = 0; jj < 2; ++jj) {
                int j = odd * 2 + jj;
                int r = m * 16 + l4 * 4 + j;
                unsigned lo = f2bf(odd ? ex[j] : gl[j]);
                unsigned hi = f2bf(odd ? gl[j] : ex[j]);
                *(unsigned*)((char*)Xs + r * 512 + (((chunk0 ^ r) << 4) | (colb & 15))) =
                    lo | (hi << 16);
            }
        }
    }
    __syncthreads();
    {
        char* Yrow = (char*)(Y + ((size_t)e * BE + row0) * 256);
#pragma unroll
        for (int i = 0; i < 4; ++i) {
            int flat = i * 4096 + t * 16;
            int r = flat >> 9;
            int chunk = (flat >> 4) & 31;
            int4 v = *(const int4*)((const char*)Xs + r * 512 + ((chunk ^ r) << 4));
            *(int4*)(Yrow + flat) = v;
        }
    }
}

// Gather expert outputs (bf16), gate, add residual, write NCHW. One block per (n,y) row.
__global__ __launch_bounds__(256) void k_gather(const float* __restrict__ input,
                                                const unsigned short* __restrict__ Y,
                                                const int2* __restrict__ slots,
                                                const float2* __restrict__ gates,
                                                const float* __restrict__ ls,
                                                float* __restrict__ out) {
    __shared__ float acc[32][257];
    int t = threadIdx.x;
    int n = blockIdx.x >> 5, y = blockIdx.x & 31;

    {   // step 1: per-token gated contribution into LDS [token][c]
        int tl = t & 31, chunk = t >> 5;
        int tok = n * 1024 + y * 32 + tl;
        int2  sl = slots[tok];
        float2 gw = gates[tok];
        int c0 = chunk * 32;
#pragma unroll
        for (int i = 0; i < 4; ++i) {
            int c = c0 + i * 8;
            float v[8];
#pragma unroll
            for (int k = 0; k < 8; ++k) v[k] = 0.f;
            if (sl.x >= 0) {
                bf16x8 yv = *(const bf16x8*)(Y + (size_t)sl.x * 256 + c);
#pragma unroll
                for (int k = 0; k < 8; ++k) v[k] += gw.x * bf2f((unsigned short)yv[k]);
            }
            if (sl.y >= 0) {
                bf16x8 yv = *(const bf16x8*)(Y + (size_t)sl.y * 256 + c);
#pragma unroll
                for (int k = 0; k < 8; ++k) v[k] += gw.y * bf2f((unsigned short)yv[k]);
            }
#pragma unroll
            for (int k = 0; k < 8; ++k) acc[tl][c + k] = v[k];
        }
    }
    __syncthreads();
    {   // step 2: out[n,c,y,x] = input + ls[c] * acc[x][c], coalesced
        int x = t & 31, c8 = t >> 5;
        size_t base = (size_t)n * 256 * 1024 + (size_t)y * 32 + x;
#pragma unroll
        for (int p = 0; p < 32; ++p) {
            int c = p * 8 + c8;
            size_t id = base + (size_t)c * 1024;
            out[id] = input[id] + ls[c] * acc[x][c];
        }
    }
}

extern "C" void kernel_launch(void* const* d_in, const int* in_sizes, int n_in,
                              void* d_out, int out_size, void* d_ws, size_t ws_size,
                              hipStream_t stream) {
    const float* input = (const float*)d_in[0];
    const float* dwk   = (const float*)d_in[1];
    const float* dwb   = (const float*)d_in[2];
    const float* gamma = (const float*)d_in[3];
    const float* beta  = (const float*)d_in[4];
    const float* rw    = (const float*)d_in[5];
    const float* w1    = (const float*)d_in[6];
    const float* b1    = (const float*)d_in[7];
    const float* w2    = (const float*)d_in[8];
    const float* b2    = (const float*)d_in[9];
    const float* ls    = (const float*)d_in[10];

    char* ws = (char*)d_ws;
    // Y (40MiB bf16) aliases xc (32MiB f32): xc is dead before k_mlp writes Y.
    unsigned short* Yb   = (unsigned short*)ws;
    float*          xc   = (float*)ws;
    unsigned short* xln  = (unsigned short*)(ws + 83886080);   // 16MB
    unsigned short* w1t  = (unsigned short*)(ws + 100663296);  // 4MB
    unsigned short* w2t  = (unsigned short*)(ws + 104857600);  // 4MB
    int*            rtok = (int*)(ws + 109051904);             // 320KB
    int2*           slots = (int2*)(ws + 109379584);           // 256KB
    float2*         gates = (float2*)(ws + 109641728);         // 256KB
    int*            e01  = (int*)(ws + 109903872);             // 128KB
    int*            cnt  = (int*)(ws + 110035968);             // 8*64 ints

    k_init<<<1, NE * CNT_STRIDE, 0, stream>>>(cnt);
    k_conv<<<32768, 256, 0, stream>>>(input, dwk, dwb, xc);
    k_ln_router<<<8192, 256, 0, stream>>>(xc, gamma, beta, rw, xln, e01, gates);
    k_assign<<<128, 256, 0, stream>>>(e01, cnt, rtok, slots);
    k_transpose<<<dim3(32, 8, 8), 256, 0, stream>>>(w1, w1t, 256, 1024);  // w1t[e][h][c]
    k_transpose<<<dim3(8, 32, 8), 256, 0, stream>>>(w2, w2t, 1024, 256);  // w2t[e][c][h]
    k_mlp<<<2560, 256, 0, stream>>>(xln, w1t, w2t, b1, b2, cnt, rtok, Yb);
    k_gather<<<1024, 256, 0, stream>>>(input, Yb, slots, gates, ls, (float*)d_out);
}

// Round 7
// 359.989 us; speedup vs baseline: 1.8730x; 1.8730x over previous
//
#include <hip/hip_runtime.h>
#include <math.h>

#define TOK 32768
#define CH  256
#define HIDN 1024
#define NE  8
#define BE  10240
#define CNT_STRIDE 64

typedef __attribute__((ext_vector_type(8))) short bf16x8;
typedef __attribute__((ext_vector_type(4))) float f32x4;

__device__ __forceinline__ unsigned short f2bf(float f) {
    unsigned u = __builtin_bit_cast(unsigned, f);
    unsigned r = 0x7FFFu + ((u >> 16) & 1u);
    return (unsigned short)((u + r) >> 16);
}
__device__ __forceinline__ float bf2f(unsigned short u) {
    return __builtin_bit_cast(float, (unsigned)u << 16);
}
__device__ __forceinline__ unsigned pk8_lo(float a, float b, unsigned old) {
    return (unsigned)__builtin_amdgcn_cvt_pk_fp8_f32(a, b, (int)old, false);
}
__device__ __forceinline__ unsigned pk8_hi(float a, float b, unsigned old) {
    return (unsigned)__builtin_amdgcn_cvt_pk_fp8_f32(a, b, (int)old, true);
}
__device__ __forceinline__ f32x4 mfma8(long a, long b, f32x4 c) {
    return __builtin_amdgcn_mfma_f32_16x16x32_fp8_fp8(a, b, c, 0, 0, 0);
}

typedef __attribute__((address_space(3))) void lds_t;
typedef const __attribute__((address_space(1))) void gm_t;
#define GL16(gp, lp) __builtin_amdgcn_global_load_lds((gm_t*)(gp), (lds_t*)(lp), 16, 0, 0)

__global__ void k_init(int* cnt) { cnt[threadIdx.x] = 0; }

// Depthwise 7x7 conv + bias, NCHW in -> NHWC (token-major) out.
__global__ __launch_bounds__(256) void k_conv(const float* __restrict__ in,
                                              const float* __restrict__ kern,
                                              const float* __restrict__ bias,
                                              float* __restrict__ xc) {
    __shared__ float kw[49];
    int t = threadIdx.x;
    int id = blockIdx.x * 256 + t;
    int x = id & 31, y = (id >> 5) & 31, c = (id >> 10) & 255, n = id >> 18;
    if (t < 49) kw[t] = kern[c * 49 + t];
    __syncthreads();
    const float* ip = in + (size_t)(n * CH + c) * 1024;
    float s = bias[c];
#pragma unroll
    for (int dy = -3; dy <= 3; ++dy) {
        int yy = y + dy;
        if ((unsigned)yy < 32u) {
            const float* rp = ip + yy * 32;
#pragma unroll
            for (int dx = -3; dx <= 3; ++dx) {
                int xx = x + dx;
                if ((unsigned)xx < 32u) s += rp[xx] * kw[(dy + 3) * 7 + (dx + 3)];
            }
        }
    }
    int token = n * 1024 + y * 32 + x;
    xc[(size_t)token * CH + c] = s;
}

// LayerNorm + router top-2. Writes x in fp8 (e4m3). One wave per token.
__global__ __launch_bounds__(256) void k_ln_router(const float* __restrict__ xc,
                                                   const float* __restrict__ gamma,
                                                   const float* __restrict__ beta,
                                                   const float* __restrict__ rw,
                                                   unsigned* __restrict__ xf8,
                                                   int* __restrict__ e01,
                                                   float2* __restrict__ gates) {
    int lane = threadIdx.x & 63;
    int wid  = threadIdx.x >> 6;
    int tok  = blockIdx.x * 4 + wid;

    const float4* xr = (const float4*)(xc + (size_t)tok * CH);
    float4 v = xr[lane];
    float s = v.x + v.y + v.z + v.w;
    float q = v.x * v.x + v.y * v.y + v.z * v.z + v.w * v.w;
#pragma unroll
    for (int m = 1; m < 64; m <<= 1) { s += __shfl_xor(s, m); q += __shfl_xor(q, m); }
    float mean = s * (1.0f / 256.0f);
    float var  = q * (1.0f / 256.0f) - mean * mean;
    float rstd = rsqrtf(var + 1e-6f);

    float4 g4 = ((const float4*)gamma)[lane];
    float4 b4 = ((const float4*)beta)[lane];
    float xn[4];
    xn[0] = (v.x - mean) * rstd * g4.x + b4.x;
    xn[1] = (v.y - mean) * rstd * g4.y + b4.y;
    xn[2] = (v.z - mean) * rstd * g4.z + b4.z;
    xn[3] = (v.w - mean) * rstd * g4.w + b4.w;

    unsigned px = pk8_lo(xn[0], xn[1], 0u);
    px = pk8_hi(xn[2], xn[3], px);
    xf8[tok * 64 + lane] = px;

    float p[8] = {0, 0, 0, 0, 0, 0, 0, 0};
    int c0 = lane * 4;
#pragma unroll
    for (int j = 0; j < 4; ++j) {
        const float* rwp = rw + (size_t)(c0 + j) * 8;
        float xv = xn[j];
#pragma unroll
        for (int e = 0; e < 8; ++e) p[e] += xv * rwp[e];
    }
#pragma unroll
    for (int m = 1; m < 64; m <<= 1) {
#pragma unroll
        for (int e = 0; e < 8; ++e) p[e] += __shfl_xor(p[e], m);
    }

    if (lane == 0) {
        int e0 = 0; float l0 = p[0];
#pragma unroll
        for (int e = 1; e < 8; ++e) if (p[e] > l0) { l0 = p[e]; e0 = e; }
        int e1 = -1; float l1 = -3.4e38f;
#pragma unroll
        for (int e = 0; e < 8; ++e) if (e != e0 && p[e] > l1) { l1 = p[e]; e1 = e; }
        float tt = expf(l1 - l0);
        float w0 = 1.0f / (1.0f + tt);
        e01[tok] = e0 | (e1 << 8);
        gates[tok] = make_float2(w0, 1.0f - w0);
    }
}

// Hierarchical capacity assignment.
__global__ __launch_bounds__(256) void k_assign(const int* __restrict__ e01,
                                                int* __restrict__ cnt,
                                                int* __restrict__ row_token,
                                                int2* __restrict__ slots) {
    __shared__ int lcnt[8];
    __shared__ int base[8];
    int t = threadIdx.x;
    if (t < 8) lcnt[t] = 0;
    __syncthreads();
    int tok = blockIdx.x * 256 + t;
    int ee = e01[tok];
    int e0 = ee & 255, e1 = (ee >> 8) & 255;
    int lp0 = atomicAdd(&lcnt[e0], 1);
    int lp1 = atomicAdd(&lcnt[e1], 1);
    __syncthreads();
    if (t < 8) base[t] = atomicAdd(cnt + t * CNT_STRIDE, lcnt[t]);
    __syncthreads();
    int pos0 = base[e0] + lp0;
    int pos1 = base[e1] + lp1;
    int slot0 = (pos0 < BE) ? e0 * BE + pos0 : -1;
    int slot1 = (pos1 < BE) ? e1 * BE + pos1 : -1;
    if (slot0 >= 0) row_token[slot0] = tok;
    if (slot1 >= 0) row_token[slot1] = tok;
    slots[tok] = make_int2(slot0, slot1);
}

// Transpose R x S (f32) -> S x R (fp8 e4m3), one matrix per blockIdx.z.
__global__ __launch_bounds__(256) void k_transpose8(const float* __restrict__ in,
                                                    unsigned char* __restrict__ out,
                                                    int R, int S) {
    __shared__ float tile[32][33];
    in += (size_t)blockIdx.z * R * S;
    out += (size_t)blockIdx.z * R * S;
    int tx = threadIdx.x & 31, ty = threadIdx.x >> 5;
    int sc = blockIdx.x * 32 + tx;
#pragma unroll
    for (int i = 0; i < 4; ++i) {
        int r = blockIdx.y * 32 + ty + i * 8;
        tile[ty + i * 8][tx] = in[(size_t)r * S + sc];
    }
    __syncthreads();
    int s = blockIdx.x * 32 + tx;
    int r0 = blockIdx.y * 32 + ty * 4;
    float v0 = tile[ty * 4 + 0][tx], v1 = tile[ty * 4 + 1][tx];
    float v2 = tile[ty * 4 + 2][tx], v3 = tile[ty * 4 + 3][tx];
    unsigned pk = pk8_lo(v0, v1, 0u);
    pk = pk8_hi(v2, v3, pk);
    *(unsigned*)(out + (size_t)s * R + r0) = pk;
}

// Fused expert MLP, fp8, weights LDS-staged via global_load_lds (double-buffered),
// X in VGPRs. Block = 512 threads (8 waves), 128 rows of one expert (e = bid&7).
// 16 steps of 64 hid; per step: STAGE(next) || A(hc)=W1@X -> gelu -> Hs || B(hc-1).
__global__ __launch_bounds__(512, 2) void k_mlp(const unsigned char* __restrict__ xf8,
                                                const unsigned char* __restrict__ w1t8, // [E][1024][256]
                                                const unsigned char* __restrict__ w2t8, // [E][256][1024]
                                                const float* __restrict__ b1,
                                                const float* __restrict__ b2,
                                                const int* __restrict__ cnt,
                                                const int* __restrict__ row_token,
                                                unsigned short* __restrict__ Y) {
    int bid = blockIdx.x;
    int e = bid & 7;
    int row0 = (bid >> 3) * 128;
    int nrows = min(cnt[e * CNT_STRIDE], BE);
    if (row0 >= nrows) return;

    // LDS: Xs[128][272] | W1 dbuf 2x[64][272] | W2 dbuf 2x[256][80] | H dbuf 2x[128][80]
    __shared__ char smem[131072];
    __shared__ int tokl[128];
    char* Xs   = smem;                    // 34816
    char* W1b0 = smem + 34816;            // 17408
    char* W1b1 = smem + 52224;            // 17408
    char* W2b0 = smem + 69632;            // 20480
    char* W2b1 = smem + 90112;            // 20480
    char* Hb0  = smem + 110592;           // 10240
    char* Hb1  = smem + 120832;           // 10240
    char* Ystage = smem + 34816;          // 64KB, reuses W areas after loop

    int t = threadIdx.x;
    int w = t >> 6, lane = t & 63;
    int l15 = lane & 15, l4 = lane >> 4;

    const unsigned char* w1e = w1t8 + (size_t)e * HIDN * 256;
    const unsigned char* w2e = w2t8 + (size_t)e * 256 * HIDN;

    // staging address precompute (thread-invariant across steps)
    int w1g[3], w2g[3];
#pragma unroll
    for (int rd = 0; rd < 3; ++rd) {
        int p = rd * 512 + t;
        int r1 = p / 17, c1 = p % 17; if (c1 > 15) c1 = 15;
        w1g[rd] = r1 * 256 + c1 * 16;
        int r2 = p / 5, c2 = p % 5; if (c2 > 3) c2 = 3;
        w2g[rd] = r2 * 1024 + c2 * 16;
    }
    int ldsoff[3];
#pragma unroll
    for (int rd = 0; rd < 3; ++rd) ldsoff[rd] = rd * 8192 + w * 1024;

    auto StageW1 = [&](int hc, char* dst) {
        const unsigned char* g = w1e + hc * 16384;
        GL16(g + w1g[0], dst + ldsoff[0]);
        GL16(g + w1g[1], dst + ldsoff[1]);
        if (w == 0) GL16(g + w1g[2], dst + ldsoff[2]);
    };
    auto StageW2 = [&](int hc, char* dst) {
        const unsigned char* g = w2e + hc * 64;
        GL16(g + w2g[0], dst + ldsoff[0]);
        GL16(g + w2g[1], dst + ldsoff[1]);
        if (w < 4) GL16(g + w2g[2], dst + ldsoff[2]);
    };

    if (t < 128) tokl[t] = (row0 + t < nrows) ? row_token[e * BE + row0 + t] : 0;
    __syncthreads();

    {   // stage Xs: 4 threads/row, 16B chunks; rows padded to 272B
        int r = t >> 2;
        const unsigned char* src = xf8 + (size_t)tokl[r] * 256;
#pragma unroll
        for (int i = 0; i < 4; ++i) {
            int c = (t & 3) + i * 4;
            *(int4*)(Xs + r * 272 + c * 16) = *(const int4*)(src + c * 16);
        }
    }
    StageW1(0, W1b0);
    __syncthreads();

    int hg = w & 3, tg = w >> 2;   // A-part: wave covers hid rows hg*16.., tok cols tg*64..
    // X -> regs: 4 tok-frags x 8 k-slices for this wave's tok-group
    long xr[4][8];
#pragma unroll
    for (int tf = 0; tf < 4; ++tf)
#pragma unroll
        for (int ks = 0; ks < 8; ++ks) {
            int row = tg * 64 + tf * 16 + l15;
            xr[tf][ks] = *(const long*)(Xs + row * 272 + ks * 32 + l4 * 8);
        }

    f32x4 yacc[16];
#pragma unroll
    for (int nc = 0; nc < 16; ++nc) yacc[nc] = f32x4{0.f, 0.f, 0.f, 0.f};

    // A-part: Ht[64 hid][128 tok] for chunk hc; gelu; packed b32 writes to H
    auto Apart = [&](int hc, const char* W1c, char* Hc) {
        long w1f[8];
#pragma unroll
        for (int ks = 0; ks < 8; ++ks)
            w1f[ks] = *(const long*)(W1c + (hg * 16 + l15) * 272 + ks * 32 + l4 * 8);
        f32x4 ha[4];
#pragma unroll
        for (int tf = 0; tf < 4; ++tf) ha[tf] = f32x4{0.f, 0.f, 0.f, 0.f};
#pragma unroll
        for (int ks = 0; ks < 8; ++ks)
#pragma unroll
            for (int tf = 0; tf < 4; ++tf)
                ha[tf] = mfma8(w1f[ks], xr[tf][ks], ha[tf]);
        float4 bb = *(const float4*)(b1 + e * HIDN + hc * 64 + hg * 16 + l4 * 4);
#pragma unroll
        for (int tf = 0; tf < 4; ++tf) {
            float g[4];
#pragma unroll
            for (int j = 0; j < 4; ++j) {
                float vv = ha[tf][j] + ((const float*)&bb)[j];
                float tt = vv * (1.0f + 0.044715f * vv * vv);
                g[j] = vv * __builtin_amdgcn_rcpf(1.0f + __builtin_amdgcn_exp2f(-2.3022100f * tt));
            }
            unsigned pk = pk8_lo(g[0], g[1], 0u);
            pk = pk8_hi(g[2], g[3], pk);
            int tok = tg * 64 + tf * 16 + l15;
            *(unsigned*)(Hc + tok * 80 + hg * 16 + l4 * 4) = pk;
        }
    };

    // B-part: Y[128 tok][256 out] += H(hp) @ W2(hp); wave owns tok rows w*16..
    auto Bpart = [&](const char* W2c, const char* Hp) {
        long ah[2];
#pragma unroll
        for (int ks = 0; ks < 2; ++ks)
            ah[ks] = *(const long*)(Hp + (w * 16 + l15) * 80 + ks * 32 + l4 * 8);
#pragma unroll
        for (int nc = 0; nc < 16; ++nc) {
#pragma unroll
            for (int ks = 0; ks < 2; ++ks) {
                long w2f = *(const long*)(W2c + (nc * 16 + l15) * 80 + ks * 32 + l4 * 8);
                yacc[nc] = mfma8(ah[ks], w2f, yacc[nc]);
            }
        }
    };

    for (int h2 = 0; h2 < 16; h2 += 2) {
        StageW1(h2 + 1, W1b1);
        StageW2(h2, W2b0);
        Apart(h2, W1b0, Hb0);
        if (h2 > 0) Bpart(W2b1, Hb1);
        __syncthreads();
        if (h2 + 2 < 16) StageW1(h2 + 2, W1b0);
        StageW2(h2 + 1, W2b1);
        Apart(h2 + 1, W1b1, Hb1);
        Bpart(W2b0, Hb0);
        __syncthreads();
    }
    Bpart(W2b1, Hb1);   // hid chunk 15
    __syncthreads();

    // stage Y (+b2, ->bf16) into Ystage [128][256] bf16, then coalesced copy-out
#pragma unroll
    for (int nc = 0; nc < 16; ++nc) {
        int col = nc * 16 + l15;
        float b2v = b2[e * 256 + col];
#pragma unroll
        for (int j = 0; j < 4; ++j) {
            int tok = w * 16 + l4 * 4 + j;
            *(unsigned short*)(Ystage + tok * 512 + col * 2) = f2bf(yacc[nc][j] + b2v);
        }
    }
    __syncthreads();
    {
        char* Yg = (char*)(Y + ((size_t)e * BE + row0) * 256);
#pragma unroll
        for (int i = 0; i < 8; ++i) {
            int flat = i * 8192 + t * 16;
            *(int4*)(Yg + flat) = *(const int4*)(Ystage + flat);
        }
    }
}

// Gather expert outputs (bf16), gate, add residual, write NCHW.
__global__ __launch_bounds__(256) void k_gather(const float* __restrict__ input,
                                                const unsigned short* __restrict__ Y,
                                                const int2* __restrict__ slots,
                                                const float2* __restrict__ gates,
                                                const float* __restrict__ ls,
                                                float* __restrict__ out) {
    __shared__ float acc[32][257];
    int t = threadIdx.x;
    int n = blockIdx.x >> 5, y = blockIdx.x & 31;

    {
        int tl = t & 31, chunk = t >> 5;
        int tok = n * 1024 + y * 32 + tl;
        int2  sl = slots[tok];
        float2 gw = gates[tok];
        int c0 = chunk * 32;
#pragma unroll
        for (int i = 0; i < 4; ++i) {
            int c = c0 + i * 8;
            float v[8];
#pragma unroll
            for (int k = 0; k < 8; ++k) v[k] = 0.f;
            if (sl.x >= 0) {
                bf16x8 yv = *(const bf16x8*)(Y + (size_t)sl.x * 256 + c);
#pragma unroll
                for (int k = 0; k < 8; ++k) v[k] += gw.x * bf2f((unsigned short)yv[k]);
            }
            if (sl.y >= 0) {
                bf16x8 yv = *(const bf16x8*)(Y + (size_t)sl.y * 256 + c);
#pragma unroll
                for (int k = 0; k < 8; ++k) v[k] += gw.y * bf2f((unsigned short)yv[k]);
            }
#pragma unroll
            for (int k = 0; k < 8; ++k) acc[tl][c + k] = v[k];
        }
    }
    __syncthreads();
    {
        int x = t & 31, c8 = t >> 5;
        size_t base = (size_t)n * 256 * 1024 + (size_t)y * 32 + x;
#pragma unroll
        for (int p = 0; p < 32; ++p) {
            int c = p * 8 + c8;
            size_t id = base + (size_t)c * 1024;
            out[id] = input[id] + ls[c] * acc[x][c];
        }
    }
}

extern "C" void kernel_launch(void* const* d_in, const int* in_sizes, int n_in,
                              void* d_out, int out_size, void* d_ws, size_t ws_size,
                              hipStream_t stream) {
    const float* input = (const float*)d_in[0];
    const float* dwk   = (const float*)d_in[1];
    const float* dwb   = (const float*)d_in[2];
    const float* gamma = (const float*)d_in[3];
    const float* beta  = (const float*)d_in[4];
    const float* rw    = (const float*)d_in[5];
    const float* w1    = (const float*)d_in[6];
    const float* b1    = (const float*)d_in[7];
    const float* w2    = (const float*)d_in[8];
    const float* b2    = (const float*)d_in[9];
    const float* ls    = (const float*)d_in[10];

    char* ws = (char*)d_ws;
    // Y (40MiB bf16) aliases xc (32MiB f32): xc dead before k_mlp writes Y.
    unsigned short* Yb   = (unsigned short*)ws;
    float*          xc   = (float*)ws;
    unsigned*       xf8  = (unsigned*)(ws + 83886080);         // 8MB fp8 x
    unsigned char*  w1t8 = (unsigned char*)(ws + 100663296);   // 2MB
    unsigned char*  w2t8 = (unsigned char*)(ws + 104857600);   // 2MB
    int*            rtok = (int*)(ws + 109051904);             // 320KB
    int2*           slots = (int2*)(ws + 109379584);           // 256KB
    float2*         gates = (float2*)(ws + 109641728);         // 256KB
    int*            e01  = (int*)(ws + 109903872);             // 128KB
    int*            cnt  = (int*)(ws + 110035968);             // 8*64 ints

    k_init<<<1, NE * CNT_STRIDE, 0, stream>>>(cnt);
    k_conv<<<32768, 256, 0, stream>>>(input, dwk, dwb, xc);
    k_ln_router<<<8192, 256, 0, stream>>>(xc, gamma, beta, rw, xf8, e01, gates);
    k_assign<<<128, 256, 0, stream>>>(e01, cnt, rtok, slots);
    k_transpose8<<<dim3(32, 8, 8), 256, 0, stream>>>(w1, w1t8, 256, 1024);  // [E][1024][256]
    k_transpose8<<<dim3(8, 32, 8), 256, 0, stream>>>(w2, w2t8, 1024, 256);  // [E][256][1024]
    k_mlp<<<640, 512, 0, stream>>>((const unsigned char*)xf8, w1t8, w2t8, b1, b2, cnt, rtok, Yb);
    k_gather<<<1024, 256, 0, stream>>>(input, Yb, slots, gates, ls, (float*)d_out);
}